// Round 8
// baseline (237.172 us; speedup 1.0000x reference)
//
#include <hip/hip_runtime.h>
#include <math.h>

// Problem: B=4, S=4096, D=2048, E=64, TOP_K=2
#define M_TOK 16384
#define D_DIM 2048
#define E_EXP 64
#define BM    32               // tokens per block (grid 512 -> 2 blocks/CU)
#define NT_H  16               // K64 tiles per K-half (2 halves -> 32 tiles = 2048 K)
#define FRAG_B 1040            // A-frag stride: 1024B payload + 16B pad
#define TILE_B (12 * FRAG_B)   // 12 frags (4 ksteps x 3 limbs) per K64 tile = 12480 B
#define LL_LD 132              // epilogue logits row stride (floats)
#define SMEM_BYTES (4 * TILE_B) // 49920 B >= epilogue 2*32*132*4 = 33792

typedef float         f32x16 __attribute__((ext_vector_type(16)));
typedef short         bf16x8 __attribute__((ext_vector_type(8)));
typedef unsigned int  uint;

#define MFMA32(a, b, c) __builtin_amdgcn_mfma_f32_32x32x16_bf16((a), (b), (c), 0, 0, 0)

// f32 -> bf16 round-to-nearest-even
__device__ __forceinline__ unsigned short bfrne(float f) {
    unsigned int u = __float_as_uint(f);
    return (unsigned short)((u + 0x7fffu + ((u >> 16) & 1u)) >> 16);
}
__device__ __forceinline__ float bfhi(unsigned short h) {
    return __uint_as_float((unsigned int)h << 16);
}

// jax.lax.top_k order: larger value first; ties -> lower index first
__device__ __forceinline__ bool beats(float va, int ia, float vb, int ib) {
    return (va > vb) || (va == vb && ia < ib);
}

// Barrier draining ONLY LDS ops: global loads (into private regs) stay in flight
// across it; the compiler emits counted vmcnt waits at first use (T4 pattern).
__device__ __forceinline__ void block_sync_lds() {
    asm volatile("s_waitcnt lgkmcnt(0)" ::: "memory");   // ds ops visible/complete
    __builtin_amdgcn_s_barrier();
    asm volatile("" ::: "memory");                        // no hoisting above
}

// ---------------- prep: split W into 3 bf16 limbs (RNE^3) as 32x32x16 B-frags ---------
// Wg (16B units): [kstep 0..127][limb 0..2][ch 0..3][lane 0..63]
//   frag lane l: col = ch*32 + (l&31)  (cols 0..63 route, 64..127 noise)
//                k   = kstep*16 + (l>>5)*8 + j   (exact mfma_32x32x16 B-frag order)
__global__ __launch_bounds__(256) void prep_w(
    const float* __restrict__ Wr, const float* __restrict__ Wn,
    unsigned short* __restrict__ Wg)
{
    const int g     = blockIdx.x * 256 + threadIdx.x;  // 0..32767
    const int lane  = g & 63;
    const int ch    = (g >> 6) & 3;
    const int kstep = g >> 8;                          // 0..127
    const int col   = ch * 32 + (lane & 31);
    const float* __restrict__ W = (col < 64) ? Wr : Wn;
    const int colL  = col & 63;
    const int kbase = kstep * 16 + (lane >> 5) * 8;

    bf16x8 o0, o1, o2;
    #pragma unroll
    for (int j = 0; j < 8; ++j) {
        const float w = W[(size_t)(kbase + j) * E_EXP + colL];
        const unsigned short h0 = bfrne(w);
        const float r  = w - bfhi(h0);              // exact
        const unsigned short h1 = bfrne(r);
        const float r2 = r - bfhi(h1);              // exact
        const unsigned short h2 = bfrne(r2);        // residual <= 2^-26 |w|
        o0[j] = (short)h0; o1[j] = (short)h1; o2[j] = (short)h2;
    }
    #pragma unroll
    for (int p = 0; p < 3; ++p) {
        const size_t idx = (((size_t)kstep * 3 + p) * 4 + ch) * 64 + lane;
        const bf16x8 o = (p == 0) ? o0 : (p == 1) ? o1 : o2;
        *(bf16x8*)(Wg + idx * 8) = o;
    }
}

// ---------------- fused: 3-limb bf16 32x32x16 MFMA + softplus + top-2 + softmax -------
// load 6 B-frags (2 ksteps x 3 limbs) for tile t starting at kstep-pair s0
__device__ __forceinline__ void load_b_half(const unsigned short* __restrict__ Wg,
                                            int t, int s0, int wc, int lane,
                                            bf16x8 (&Bv)[2][3])
{
    #pragma unroll
    for (int s = 0; s < 2; ++s) {
        const int kstep = t * 4 + s0 + s;
        #pragma unroll
        for (int p = 0; p < 3; ++p) {
            const size_t idx = (((size_t)kstep * 3 + p) * 4 + wc);
            Bv[s][p] = *(const bf16x8*)(Wg + (idx << 9) + lane * 8);
        }
    }
}

// A tile 32 tok x 64 k: one float4 per thread (512 threads * 16B = 8KB f32)
__device__ __forceinline__ void load_a(const float* __restrict__ A, int tokBase,
                                       int t, int tid, float4& x)
{
    const int row = tid >> 4;          // 0..31
    const int kc  = tid & 15;
    x = *(const float4*)(A + (size_t)(tokBase + row) * D_DIM + t * 64 + kc * 4);
}

// split 4 floats -> 3 limb 8B pieces, scatter into frag-linear tile buffer.
// limbs 0,1 truncation (exact residuals), limb 2 RNE; residual <= 2^-22 rel
// (verified numerics of rounds 1-6; 2-limb was refuted in round 7).
__device__ __forceinline__ void cvt_store(char* tbase, int tid, const float4& x)
{
    const float v[4] = {x.x, x.y, x.z, x.w};
    uint t0[4], t1[4]; unsigned short h2[4];
    #pragma unroll
    for (int j = 0; j < 4; ++j) {
        const uint u = __float_as_uint(v[j]);
        t0[j] = u & 0xffff0000u;
        const float r = v[j] - __uint_as_float(t0[j]);      // exact
        const uint ru = __float_as_uint(r);
        t1[j] = ru & 0xffff0000u;
        const float r2 = r - __uint_as_float(t1[j]);        // exact
        h2[j] = bfrne(r2);
    }
    uint2 w0, w1, w2;
    w0.x = (t0[0] >> 16) | t0[1];  w0.y = (t0[2] >> 16) | t0[3];
    w1.x = (t1[0] >> 16) | t1[1];  w1.y = (t1[2] >> 16) | t1[3];
    w2.x = (uint)h2[0] | ((uint)h2[1] << 16);
    w2.y = (uint)h2[2] | ((uint)h2[3] << 16);

    const int row   = tid >> 4;
    const int kc    = tid & 15;         // k = kc*4 within the 64-wide tile
    const int kstep = kc >> 2;          // 0..3
    const int hoct  = (kc >> 1) & 1;    // k-octet within kstep
    const int half  = kc & 1;           // lower/upper 8B of the lane's 16B
    const int l     = hoct * 32 + row;  // frag lane index
    char* p = tbase + kstep * (3 * FRAG_B) + l * 16 + half * 8;
    *(uint2*)(p)              = w0;
    *(uint2*)(p + FRAG_B)     = w1;
    *(uint2*)(p + 2 * FRAG_B) = w2;
}

// 2 ksteps: 6 linear ds_read_b128 + 12 MFMA(32x32x16)
__device__ __forceinline__ void compute_half(const char* buf, int s0, int lane,
                                             const bf16x8 (&Bv)[2][3],
                                             f32x16& acch, f32x16& accl)
{
    const char* ap = buf + lane * 16;
    #pragma unroll
    for (int s = 0; s < 2; ++s) {
        const int f = (s0 + s) * 3;
        const bf16x8 a0 = *(const bf16x8*)(ap + (f + 0) * FRAG_B);
        const bf16x8 a1 = *(const bf16x8*)(ap + (f + 1) * FRAG_B);
        const bf16x8 a2 = *(const bf16x8*)(ap + (f + 2) * FRAG_B);
        // hi product -> short dep chain in acch; 5 low products -> accl
        acch = MFMA32(a0, Bv[s][0], acch);
        accl = MFMA32(a0, Bv[s][1], accl);
        accl = MFMA32(a1, Bv[s][0], accl);
        accl = MFMA32(a1, Bv[s][1], accl);
        accl = MFMA32(a0, Bv[s][2], accl);
        accl = MFMA32(a2, Bv[s][0], accl);
    }
}

__global__ __launch_bounds__(512, 4) void fused_router(
    const float* __restrict__ A,
    const unsigned short* __restrict__ Wg,
    const float* __restrict__ br, const float* __restrict__ bn,
    const float* __restrict__ noise,
    float* __restrict__ probs, float* __restrict__ idxo)
{
    __shared__ __align__(16) char smem[SMEM_BYTES];   // 4 tile buffers; epilogue aliases

    const int tid  = threadIdx.x;
    const int lane = tid & 63;
    const int wid  = tid >> 6;       // 0..7
    const int wc   = wid & 3;        // 32-col slice of 128 (route|noise)
    const int kh   = wid >> 2;       // K half: tiles [0,16) or [16,32)
    const int tokBase = blockIdx.x * BM;

    f32x16 acch, accl;
    #pragma unroll
    for (int r = 0; r < 16; ++r) { acch[r] = 0.f; accl[r] = 0.f; }

    char* s0a = smem;                   // kh0 parity0
    char* s0b = smem + TILE_B;          // kh0 parity1
    char* s1a = smem + 2 * TILE_B;      // kh1 parity0
    char* s1b = smem + 3 * TILE_B;      // kh1 parity1
    const char* myB0 = smem + (kh * 2 + 0) * TILE_B;
    const char* myB1 = smem + (kh * 2 + 1) * TILE_B;

    bf16x8 Bx[2][3], By[2][3];
    float4 x0, x1;

    // prologue: tiles (0,16) -> parity0; A(1,17) + B(tile kh*16, half0) in flight
    load_a(A, tokBase, 0,        tid, x0);
    load_a(A, tokBase, NT_H,     tid, x1);
    cvt_store(s0a, tid, x0);
    cvt_store(s1a, tid, x1);
    load_a(A, tokBase, 1,        tid, x0);
    load_a(A, tokBase, NT_H + 1, tid, x1);
    load_b_half(Wg, kh * NT_H, 0, wc, lane, Bx);
    block_sync_lds();

    #pragma unroll 1
    for (int it = 0; it < NT_H; it += 2) {
        const int tA = kh * NT_H + it;

        // ---- body A: stage parity1 (tile it+1); compute parity0 (tile tA) ----
        cvt_store(s0b, tid, x0);
        cvt_store(s1b, tid, x1);
        if (it + 2 < NT_H) {
            load_a(A, tokBase, it + 2,        tid, x0);      // in flight across barrier
            load_a(A, tokBase, NT_H + it + 2, tid, x1);
        }
        load_b_half(Wg, tA, 2, wc, lane, By);                // half1 in flight
        __builtin_amdgcn_s_setprio(1);
        compute_half(myB0, 0, lane, Bx, acch, accl);
        __builtin_amdgcn_s_setprio(0);
        load_b_half(Wg, tA + 1, 0, wc, lane, Bx);            // next tile half0
        __builtin_amdgcn_s_setprio(1);
        compute_half(myB0, 2, lane, By, acch, accl);
        __builtin_amdgcn_s_setprio(0);
        block_sync_lds();

        // ---- body B: stage parity0 (tile it+2); compute parity1 (tile tA+1) ----
        if (it + 2 < NT_H) {
            cvt_store(s0a, tid, x0);
            cvt_store(s1a, tid, x1);
        }
        if (it + 3 < NT_H) {
            load_a(A, tokBase, it + 3,        tid, x0);
            load_a(A, tokBase, NT_H + it + 3, tid, x1);
        }
        load_b_half(Wg, tA + 1, 2, wc, lane, By);
        __builtin_amdgcn_s_setprio(1);
        compute_half(myB1, 0, lane, Bx, acch, accl);
        __builtin_amdgcn_s_setprio(0);
        if (it + 2 < NT_H) load_b_half(Wg, tA + 2, 0, wc, lane, Bx);
        __builtin_amdgcn_s_setprio(1);
        compute_half(myB1, 2, lane, By, acch, accl);
        __builtin_amdgcn_s_setprio(0);
        block_sync_lds();
    }

    // ---- accumulators -> LDS logits; K-halves into separate slabs, summed in epilogue.
    // 32x32 C layout: col = lane&31, row = (r&3) + 8*(r>>2) + 4*(lane>>5)
    float (*Ll)[BM][LL_LD] = (float (*)[BM][LL_LD])smem;   // [2][32][132], aliases bufs
    {
        const int col   = wc * 32 + (lane & 31);
        const int rbase = 4 * (lane >> 5);
        #pragma unroll
        for (int r = 0; r < 16; ++r) {
            const int row = (r & 3) + 8 * (r >> 2) + rbase;
            Ll[kh][row][col] = acch[r] + accl[r];
        }
    }
    block_sync_lds();

    // ---- fused epilogue: 16 lanes per token, 4 experts each (f32) ----
    const int token = tid >> 4;          // 0..31
    const int s16   = tid & 15;
    const int tokG  = tokBase + token;

    float v0 = -INFINITY, v1 = -INFINITY;
    int i0 = 0, i1 = 0;
    {
        const float4 n4 = *(const float4*)(noise + (size_t)tokG * E_EXP + s16 * 4);
        const float4 b4 = *(const float4*)(br + s16 * 4);
        const float4 c4 = *(const float4*)(bn + s16 * 4);
        const float4 la = *(const float4*)(&Ll[0][token][s16 * 4]);
        const float4 lb = *(const float4*)(&Ll[1][token][s16 * 4]);
        const float4 ma = *(const float4*)(&Ll[0][token][64 + s16 * 4]);
        const float4 mb = *(const float4*)(&Ll[1][token][64 + s16 * 4]);
        const float nv[4] = {n4.x, n4.y, n4.z, n4.w};
        const float bv[4] = {b4.x, b4.y, b4.z, b4.w};
        const float cv[4] = {c4.x, c4.y, c4.z, c4.w};
        const float lv[4] = {la.x + lb.x, la.y + lb.y, la.z + lb.z, la.w + lb.w};
        const float mv[4] = {ma.x + mb.x, ma.y + mb.y, ma.z + mb.z, ma.w + mb.w};
        #pragma unroll
        for (int j = 0; j < 4; ++j) {
            const int e = s16 * 4 + j;
            const float lg = lv[j] + bv[j];
            const float nl = mv[j] + cv[j];
            const float sp = fmaxf(nl, 0.0f) + log1pf(expf(-fabsf(nl)));   // softplus
            const float v  = fmaf(nv[j], sp, lg);
            if (beats(v, e, v0, i0))      { v1 = v0; i1 = i0; v0 = v; i0 = e; }
            else if (beats(v, e, v1, i1)) { v1 = v;  i1 = e; }
        }
    }
    // merge across the token's 16 lanes (aligned group, masks 1,2,4,8)
    #pragma unroll
    for (int m = 1; m < 16; m <<= 1) {
        const float w0 = __shfl_xor(v0, m), w1 = __shfl_xor(v1, m);
        const int   j0 = __shfl_xor(i0, m), j1 = __shfl_xor(i1, m);
        if (beats(v0, i0, w0, j0)) {
            if (!beats(v1, i1, w0, j0)) { v1 = w0; i1 = j0; }
        } else {
            if (beats(v0, i0, w1, j1)) { v1 = v0; i1 = i0; }
            else                       { v1 = w1; i1 = j1; }
            v0 = w0; i0 = j0;
        }
    }
    const float e1  = expf(v1 - v0);     // <= 1
    const float den = 1.0f + e1;
    const float p0 = 1.0f / den;
    const float p1 = e1 / den;

    float out[4];
    #pragma unroll
    for (int j = 0; j < 4; ++j) {
        const int e = s16 * 4 + j;
        out[j] = (e == i0) ? p0 : ((e == i1) ? p1 : 0.0f);
    }
    *(float4*)(probs + (size_t)tokG * E_EXP + s16 * 4) =
        make_float4(out[0], out[1], out[2], out[3]);
    if (s16 == 0)
        *(float2*)(idxo + (size_t)tokG * 2) = make_float2((float)i0, (float)i1);
}

extern "C" void kernel_launch(void* const* d_in, const int* in_sizes, int n_in,
                              void* d_out, int out_size, void* d_ws, size_t ws_size,
                              hipStream_t stream) {
    (void)in_sizes; (void)n_in; (void)out_size; (void)ws_size;
    const float* A  = (const float*)d_in[0];   // mh_output [4,4096,2048]
    const float* Wr = (const float*)d_in[1];   // W_route   [2048,64]
    const float* br = (const float*)d_in[2];   // b_route   [64]
    const float* Wn = (const float*)d_in[3];   // W_noise   [2048,64]
    const float* bn = (const float*)d_in[4];   // b_noise   [64]
    const float* nz = (const float*)d_in[5];   // noise     [4,4096,64]

    float* probs = (float*)d_out;                    // [4,4096,64] f32
    float* idxo  = probs + (size_t)M_TOK * E_EXP;    // [4,4096,2] as float

    unsigned short* Wg = (unsigned short*)d_ws;      // 1.57 MB split-W, frag-linear

    prep_w<<<128, 256, 0, stream>>>(Wr, Wn, Wg);
    fused_router<<<M_TOK / BM, 512, 0, stream>>>(A, Wg, br, bn, nz, probs, idxo);
}

// Round 9
// 226.292 us; speedup vs baseline: 1.0481x; 1.0481x over previous
//
#include <hip/hip_runtime.h>
#include <math.h>

// Problem: B=4, S=4096, D=2048, E=64, TOP_K=2
#define M_TOK 16384
#define D_DIM 2048
#define E_EXP 64
#define BM    32               // tokens per block (grid 512 -> 2 blocks/CU)
#define NT_H  16               // K64 tiles per K-half (2 halves -> 32 tiles = 2048 K)
#define FRAG_B 1040            // A-frag stride: 1024B payload + 16B pad
#define TILE_B (12 * FRAG_B)   // 12 frags (4 ksteps x 3 limbs) per K64 tile = 12480 B
#define LL_LD 132              // epilogue logits row stride (floats)
#define SMEM_BYTES (4 * TILE_B) // 49920 B >= epilogue 2*32*132*4 = 33792

typedef float         f32x16 __attribute__((ext_vector_type(16)));
typedef short         bf16x8 __attribute__((ext_vector_type(8)));
typedef unsigned int  uint;

#define MFMA32(a, b, c) __builtin_amdgcn_mfma_f32_32x32x16_bf16((a), (b), (c), 0, 0, 0)

// f32 -> bf16 round-to-nearest-even
__device__ __forceinline__ unsigned short bfrne(float f) {
    unsigned int u = __float_as_uint(f);
    return (unsigned short)((u + 0x7fffu + ((u >> 16) & 1u)) >> 16);
}
__device__ __forceinline__ float bfhi(unsigned short h) {
    return __uint_as_float((unsigned int)h << 16);
}

// jax.lax.top_k order: larger value first; ties -> lower index first
__device__ __forceinline__ bool beats(float va, int ia, float vb, int ib) {
    return (va > vb) || (va == vb && ia < ib);
}

// ---------------- prep: split W into 3 bf16 limbs (RNE^3) as 32x32x16 B-frags ---------
// Wg (16B units): [kstep 0..127][limb 0..2][ch 0..3][lane 0..63]
//   frag lane l: col = ch*32 + (l&31)  (cols 0..63 route, 64..127 noise)
//                k   = kstep*16 + (l>>5)*8 + j   (exact mfma_32x32x16 B-frag order)
__global__ __launch_bounds__(256) void prep_w(
    const float* __restrict__ Wr, const float* __restrict__ Wn,
    unsigned short* __restrict__ Wg)
{
    const int g     = blockIdx.x * 256 + threadIdx.x;  // 0..32767
    const int lane  = g & 63;
    const int ch    = (g >> 6) & 3;
    const int kstep = g >> 8;                          // 0..127
    const int col   = ch * 32 + (lane & 31);
    const float* __restrict__ W = (col < 64) ? Wr : Wn;
    const int colL  = col & 63;
    const int kbase = kstep * 16 + (lane >> 5) * 8;

    bf16x8 o0, o1, o2;
    #pragma unroll
    for (int j = 0; j < 8; ++j) {
        const float w = W[(size_t)(kbase + j) * E_EXP + colL];
        const unsigned short h0 = bfrne(w);
        const float r  = w - bfhi(h0);              // exact
        const unsigned short h1 = bfrne(r);
        const float r2 = r - bfhi(h1);              // exact
        const unsigned short h2 = bfrne(r2);        // residual <= 2^-26 |w|
        o0[j] = (short)h0; o1[j] = (short)h1; o2[j] = (short)h2;
    }
    #pragma unroll
    for (int p = 0; p < 3; ++p) {
        const size_t idx = (((size_t)kstep * 3 + p) * 4 + ch) * 64 + lane;
        const bf16x8 o = (p == 0) ? o0 : (p == 1) ? o1 : o2;
        *(bf16x8*)(Wg + idx * 8) = o;
    }
}

// ---------------- fused: 3-limb bf16 32x32x16 MFMA, 8-phase schedule ----------------
// load the 3 limb B-frags of one physical kstep
__device__ __forceinline__ void load_b_k(const unsigned short* __restrict__ Wg,
                                         int kstep, int wc, int lane, bf16x8 (&B)[3])
{
    #pragma unroll
    for (int p = 0; p < 3; ++p) {
        const size_t idx = ((size_t)(kstep * 3 + p) * 4 + wc);
        B[p] = *(const bf16x8*)(Wg + (idx << 9) + lane * 8);
    }
}

// A tile 32 tok x 64 k: one float4 per thread (512 threads * 16B = 8KB f32)
__device__ __forceinline__ void load_a(const float* __restrict__ A, int tokBase,
                                       int t, int tid, float4& x)
{
    const int row = tid >> 4;          // 0..31
    const int kc  = tid & 15;
    x = *(const float4*)(A + (size_t)(tokBase + row) * D_DIM + t * 64 + kc * 4);
}

// split 4 floats -> 3 limb 8B pieces, scatter into frag-linear tile buffer.
// limbs 0,1 truncation (exact residuals), limb 2 RNE; residual <= 2^-22 rel
// (verified numerics of rounds 1-6; 2-limb was refuted in round 7).
__device__ __forceinline__ void cvt_store(char* tbase, int tid, const float4& x)
{
    const float v[4] = {x.x, x.y, x.z, x.w};
    uint t0[4], t1[4]; unsigned short h2[4];
    #pragma unroll
    for (int j = 0; j < 4; ++j) {
        const uint u = __float_as_uint(v[j]);
        t0[j] = u & 0xffff0000u;
        const float r = v[j] - __uint_as_float(t0[j]);      // exact
        const uint ru = __float_as_uint(r);
        t1[j] = ru & 0xffff0000u;
        const float r2 = r - __uint_as_float(t1[j]);        // exact
        h2[j] = bfrne(r2);
    }
    uint2 w0, w1, w2;
    w0.x = (t0[0] >> 16) | t0[1];  w0.y = (t0[2] >> 16) | t0[3];
    w1.x = (t1[0] >> 16) | t1[1];  w1.y = (t1[2] >> 16) | t1[3];
    w2.x = (uint)h2[0] | ((uint)h2[1] << 16);
    w2.y = (uint)h2[2] | ((uint)h2[3] << 16);

    const int row   = tid >> 4;
    const int kc    = tid & 15;         // k = kc*4 within the 64-wide tile
    const int kstep = kc >> 2;          // 0..3
    const int hoct  = (kc >> 1) & 1;    // k-octet within kstep
    const int half  = kc & 1;           // lower/upper 8B of the lane's 16B
    const int l     = hoct * 32 + row;  // frag lane index
    char* p = tbase + kstep * (3 * FRAG_B) + l * 16 + half * 8;
    *(uint2*)(p)              = w0;
    *(uint2*)(p + FRAG_B)     = w1;
    *(uint2*)(p + 2 * FRAG_B) = w2;
}

// One phase: {3 ds_read | 3 B-load prefetch | EXTRA work} -> bar -> lgkm0 ->
// setprio(1) 6 MFMA setprio(0) -> bar.  vmcnt is never drained in-loop (T4).
#define PHASE_BODY(P, BC, NK, BN, EXTRA) do {                        \
    const char* ap_ = cbuf + (P) * (3 * FRAG_B) + lane * 16;         \
    const bf16x8 a0_ = *(const bf16x8*)(ap_);                        \
    const bf16x8 a1_ = *(const bf16x8*)(ap_ + FRAG_B);               \
    const bf16x8 a2_ = *(const bf16x8*)(ap_ + 2 * FRAG_B);           \
    load_b_k(Wg, (NK), wc, lane, BN);                                \
    EXTRA                                                            \
    __builtin_amdgcn_s_barrier();                                    \
    asm volatile("s_waitcnt lgkmcnt(0)" ::: "memory");               \
    __builtin_amdgcn_s_setprio(1);                                   \
    acch = MFMA32(a0_, BC[0], acch);                                 \
    accl = MFMA32(a0_, BC[1], accl);                                 \
    accl = MFMA32(a1_, BC[0], accl);                                 \
    accl = MFMA32(a1_, BC[1], accl);                                 \
    accl = MFMA32(a0_, BC[2], accl);                                 \
    accl = MFMA32(a2_, BC[0], accl);                                 \
    __builtin_amdgcn_s_setprio(0);                                   \
    __builtin_amdgcn_s_barrier();                                    \
} while (0)

// One K64 tile = 4 phases. BX holds kstep0 of this tile on entry; on exit BX
// holds kstep0 of the next tile (loaded in phase 3).
__device__ __forceinline__ void run_tile(
    const float* __restrict__ A, const unsigned short* __restrict__ Wg,
    const char* cbuf, char* d0, char* d1, int t, bool do_cvt, bool do_lda,
    int tokBase, int tid, int lane, int wc, int kh,
    bf16x8 (&BX)[3], bf16x8 (&BY)[3],
    float4& x0, float4& x1, f32x16& acch, f32x16& accl)
{
    const int kbase = (kh * NT_H + t) * 4;     // physical kstep base of this tile
    PHASE_BODY(0, BX, kbase + 1, BY, );
    PHASE_BODY(1, BY, kbase + 2, BX, );
    PHASE_BODY(2, BX, kbase + 3, BY, if (do_cvt) cvt_store(d0, tid, x0); );
    PHASE_BODY(3, BY, kbase + 4, BX,
        if (do_cvt) cvt_store(d1, tid, x1);
        if (do_lda) { load_a(A, tokBase, t + 2, tid, x0);
                      load_a(A, tokBase, NT_H + t + 2, tid, x1); } );
}

__global__ __launch_bounds__(512, 4) void fused_router(
    const float* __restrict__ A,
    const unsigned short* __restrict__ Wg,
    const float* __restrict__ br, const float* __restrict__ bn,
    const float* __restrict__ noise,
    float* __restrict__ probs, float* __restrict__ idxo)
{
    __shared__ __align__(16) char smem[SMEM_BYTES];   // 4 tile buffers; epilogue aliases

    const int tid  = threadIdx.x;
    const int lane = tid & 63;
    const int wid  = tid >> 6;       // 0..7
    const int wc   = wid & 3;        // 32-col slice of 128 (route|noise)
    const int kh   = wid >> 2;       // K half: tiles [0,16) or [16,32)
    const int tokBase = blockIdx.x * BM;

    f32x16 acch, accl;
    #pragma unroll
    for (int r = 0; r < 16; ++r) { acch[r] = 0.f; accl[r] = 0.f; }

    char* s0a = smem;                   // kh0 parity0
    char* s0b = smem + TILE_B;          // kh0 parity1
    char* s1a = smem + 2 * TILE_B;      // kh1 parity0
    char* s1b = smem + 3 * TILE_B;      // kh1 parity1
    const char* myB0 = smem + (kh * 2 + 0) * TILE_B;
    const char* myB1 = smem + (kh * 2 + 1) * TILE_B;

    bf16x8 BX[3], BY[3];
    float4 x0, x1;

    // prologue: tiles (0,16) -> parity0; A(1,17) + B(kstep0 of tile kh*16) in flight
    load_a(A, tokBase, 0,        tid, x0);
    load_a(A, tokBase, NT_H,     tid, x1);
    cvt_store(s0a, tid, x0);
    cvt_store(s1a, tid, x1);
    load_a(A, tokBase, 1,        tid, x0);
    load_a(A, tokBase, NT_H + 1, tid, x1);
    load_b_k(Wg, (kh * NT_H) * 4, wc, lane, BX);
    asm volatile("s_waitcnt lgkmcnt(0)" ::: "memory");
    __builtin_amdgcn_s_barrier();
    asm volatile("" ::: "memory");

    #pragma unroll 1
    for (int t = 0; t < NT_H; t += 2) {
        // even tile: compute parity0; stage parity1 (tile t+1 data, always valid)
        run_tile(A, Wg, myB0, s0b, s1b, t, true, t + 2 < NT_H,
                 tokBase, tid, lane, wc, kh, BX, BY, x0, x1, acch, accl);
        // odd tile: compute parity1; stage parity0 (tile t+2 data, if it exists)
        run_tile(A, Wg, myB1, s0a, s1a, t + 1, t + 2 < NT_H, t + 3 < NT_H,
                 tokBase, tid, lane, wc, kh, BX, BY, x0, x1, acch, accl);
    }

    // ---- accumulators -> LDS logits; K-halves into separate slabs, summed in epilogue.
    // 32x32 C layout: col = lane&31, row = (r&3) + 8*(r>>2) + 4*(lane>>5)
    float (*Ll)[BM][LL_LD] = (float (*)[BM][LL_LD])smem;   // [2][32][132], aliases bufs
    {
        const int col   = wc * 32 + (lane & 31);
        const int rbase = 4 * (lane >> 5);
        #pragma unroll
        for (int r = 0; r < 16; ++r) {
            const int row = (r & 3) + 8 * (r >> 2) + rbase;
            Ll[kh][row][col] = acch[r] + accl[r];
        }
    }
    asm volatile("s_waitcnt lgkmcnt(0)" ::: "memory");
    __builtin_amdgcn_s_barrier();
    asm volatile("" ::: "memory");

    // ---- fused epilogue: 16 lanes per token, 4 experts each (f32) ----
    const int token = tid >> 4;          // 0..31
    const int s16   = tid & 15;
    const int tokG  = tokBase + token;

    float v0 = -INFINITY, v1 = -INFINITY;
    int i0 = 0, i1 = 0;
    {
        const float4 n4 = *(const float4*)(noise + (size_t)tokG * E_EXP + s16 * 4);
        const float4 b4 = *(const float4*)(br + s16 * 4);
        const float4 c4 = *(const float4*)(bn + s16 * 4);
        const float4 la = *(const float4*)(&Ll[0][token][s16 * 4]);
        const float4 lb = *(const float4*)(&Ll[1][token][s16 * 4]);
        const float4 ma = *(const float4*)(&Ll[0][token][64 + s16 * 4]);
        const float4 mb = *(const float4*)(&Ll[1][token][64 + s16 * 4]);
        const float nv[4] = {n4.x, n4.y, n4.z, n4.w};
        const float bv[4] = {b4.x, b4.y, b4.z, b4.w};
        const float cv[4] = {c4.x, c4.y, c4.z, c4.w};
        const float lv[4] = {la.x + lb.x, la.y + lb.y, la.z + lb.z, la.w + lb.w};
        const float mv[4] = {ma.x + mb.x, ma.y + mb.y, ma.z + mb.z, ma.w + mb.w};
        #pragma unroll
        for (int j = 0; j < 4; ++j) {
            const int e = s16 * 4 + j;
            const float lg = lv[j] + bv[j];
            const float nl = mv[j] + cv[j];
            const float sp = fmaxf(nl, 0.0f) + log1pf(expf(-fabsf(nl)));   // softplus
            const float v  = fmaf(nv[j], sp, lg);
            if (beats(v, e, v0, i0))      { v1 = v0; i1 = i0; v0 = v; i0 = e; }
            else if (beats(v, e, v1, i1)) { v1 = v;  i1 = e; }
        }
    }
    // merge across the token's 16 lanes (aligned group, masks 1,2,4,8)
    #pragma unroll
    for (int m = 1; m < 16; m <<= 1) {
        const float w0 = __shfl_xor(v0, m), w1 = __shfl_xor(v1, m);
        const int   j0 = __shfl_xor(i0, m), j1 = __shfl_xor(i1, m);
        if (beats(v0, i0, w0, j0)) {
            if (!beats(v1, i1, w0, j0)) { v1 = w0; i1 = j0; }
        } else {
            if (beats(v0, i0, w1, j1)) { v1 = v0; i1 = i0; }
            else                       { v1 = w1; i1 = j1; }
            v0 = w0; i0 = j0;
        }
    }
    const float e1  = expf(v1 - v0);     // <= 1
    const float den = 1.0f + e1;
    const float p0 = 1.0f / den;
    const float p1 = e1 / den;

    float out[4];
    #pragma unroll
    for (int j = 0; j < 4; ++j) {
        const int e = s16 * 4 + j;
        out[j] = (e == i0) ? p0 : ((e == i1) ? p1 : 0.0f);
    }
    *(float4*)(probs + (size_t)tokG * E_EXP + s16 * 4) =
        make_float4(out[0], out[1], out[2], out[3]);
    if (s16 == 0)
        *(float2*)(idxo + (size_t)tokG * 2) = make_float2((float)i0, (float)i1);
}

extern "C" void kernel_launch(void* const* d_in, const int* in_sizes, int n_in,
                              void* d_out, int out_size, void* d_ws, size_t ws_size,
                              hipStream_t stream) {
    (void)in_sizes; (void)n_in; (void)out_size; (void)ws_size;
    const float* A  = (const float*)d_in[0];   // mh_output [4,4096,2048]
    const float* Wr = (const float*)d_in[1];   // W_route   [2048,64]
    const float* br = (const float*)d_in[2];   // b_route   [64]
    const float* Wn = (const float*)d_in[3];   // W_noise   [2048,64]
    const float* bn = (const float*)d_in[4];   // b_noise   [64]
    const float* nz = (const float*)d_in[5];   // noise     [4,4096,64]

    float* probs = (float*)d_out;                    // [4,4096,64] f32
    float* idxo  = probs + (size_t)M_TOK * E_EXP;    // [4,4096,2] as float

    unsigned short* Wg = (unsigned short*)d_ws;      // 1.57 MB split-W, frag-linear

    prep_w<<<128, 256, 0, stream>>>(Wr, Wn, Wg);
    fused_router<<<M_TOK / BM, 512, 0, stream>>>(A, Wg, br, bn, nz, probs, idxo);
}